// Round 5
// baseline (522.842 us; speedup 1.0000x reference)
//
#include <hip/hip_runtime.h>

static inline int ceil_div(int a, int b) { return (a + b - 1) / b; }

typedef __attribute__((ext_vector_type(8))) __bf16 bf16x8;
typedef __attribute__((ext_vector_type(8))) unsigned short ushort8;
typedef __attribute__((ext_vector_type(4))) float f32x4;

__device__ __forceinline__ unsigned short f2bf(float f) {
    union { float f; unsigned u; } v; v.f = f;
    unsigned r = v.u + 0x7fffu + ((v.u >> 16) & 1u);
    return (unsigned short)(r >> 16);
}
__device__ __forceinline__ float blo(unsigned u) {
    union { unsigned u; float f; } x; x.u = u << 16; return x.f;
}
__device__ __forceinline__ float bhi(unsigned u) {
    union { unsigned u; float f; } x; x.u = u & 0xffff0000u; return x.f;
}

// ---------------- fused prep: edge count + x->bf16 + weight transpose ----------------
__global__ __launch_bounds__(256) void k_prep(const int* __restrict__ dst, int E, int* __restrict__ cnt,
                                              const float* __restrict__ x, unsigned short* __restrict__ xb,
                                              long nx,
                                              const float* __restrict__ W1, const float* __restrict__ Wmu,
                                              const float* __restrict__ Wls, unsigned short* __restrict__ W1t,
                                              unsigned short* __restrict__ Wct, int K1, int H, int Cout,
                                              int nbCount, int nbX) {
    const int b = blockIdx.x;
    if (b < nbCount) {
        int e = b * 256 + threadIdx.x;
        if (e < E) atomicAdd(&cnt[dst[e]], 1);
    } else if (b < nbCount + nbX) {
        long i = (long)(b - nbCount) * 2048 + (long)threadIdx.x * 8;
        if (i < nx) {
            float4 a0 = *(const float4*)(x + i);
            float4 a1 = *(const float4*)(x + i + 4);
            ushort8 t;
            t[0] = f2bf(a0.x); t[1] = f2bf(a0.y); t[2] = f2bf(a0.z); t[3] = f2bf(a0.w);
            t[4] = f2bf(a1.x); t[5] = f2bf(a1.y); t[6] = f2bf(a1.z); t[7] = f2bf(a1.w);
            *(ushort8*)(xb + i) = t;
        }
    } else {
        int t = (b - nbCount - nbX) * 256 + threadIdx.x;
        int n1 = H * K1;
        int n2 = 2 * Cout * H;
        if (t < n1) {
            int c = t / K1, k = t - c * K1;
            W1t[t] = f2bf(W1[(size_t)k * H + c]);
        } else if (t < n1 + n2) {
            int u = t - n1;
            int c = u / H, k = u - c * H;
            float v = (c < Cout) ? Wmu[(size_t)k * Cout + c] : Wls[(size_t)k * Cout + (c - Cout)];
            Wct[u] = f2bf(v);
        }
    }
}

// ---- hierarchical exclusive scan over deg = cnt+1 (self-loop) ----
__global__ __launch_bounds__(256) void k_bsum(const int* __restrict__ cnt, int* __restrict__ bsum, int N) {
    __shared__ int ws[4];
    const int i = blockIdx.x * 256 + threadIdx.x;
    const int lane = threadIdx.x & 63, wave = threadIdx.x >> 6;
    int v = (i < N) ? cnt[i] + 1 : 0;
    for (int off = 32; off > 0; off >>= 1) v += __shfl_down(v, off);
    if (lane == 0) ws[wave] = v;
    __syncthreads();
    if (threadIdx.x == 0) bsum[blockIdx.x] = ws[0] + ws[1] + ws[2] + ws[3];
}

__global__ __launch_bounds__(256) void k_scan_bsum(const int* __restrict__ bsum, int* __restrict__ bbase,
                                                   int nb, int* __restrict__ row_ptr, int N) {
    __shared__ int ws[4];
    const int tid = threadIdx.x;
    const int lane = tid & 63, wave = tid >> 6;
    const int v = (tid < nb) ? bsum[tid] : 0;
    int x = v;
    for (int off = 1; off < 64; off <<= 1) {
        int t = __shfl_up(x, off);
        if (lane >= off) x += t;
    }
    if (lane == 63) ws[wave] = x;
    __syncthreads();
    if (tid == 0) {
        int r = 0;
        for (int i = 0; i < 4; ++i) { int t = ws[i]; ws[i] = r; r += t; }
        row_ptr[N] = r;
    }
    __syncthreads();
    if (tid < nb) bbase[tid] = ws[wave] + x - v;
}

__global__ __launch_bounds__(256) void k_scan_apply(const int* __restrict__ cnt, const int* __restrict__ bbase,
                                                    int* __restrict__ row_ptr, int* __restrict__ cursor,
                                                    float* __restrict__ dinv, int N) {
    __shared__ int ws[4];
    const int i = blockIdx.x * 256 + threadIdx.x;
    const int lane = threadIdx.x & 63, wave = threadIdx.x >> 6;
    const int c = (i < N) ? cnt[i] + 1 : 0;
    int x = c;
    for (int off = 1; off < 64; off <<= 1) {
        int t = __shfl_up(x, off);
        if (lane >= off) x += t;
    }
    if (lane == 63) ws[wave] = x;
    __syncthreads();
    if (threadIdx.x == 0) {
        int r = 0;
        for (int k = 0; k < 4; ++k) { int t = ws[k]; ws[k] = r; r += t; }
    }
    __syncthreads();
    if (i < N) {
        const int excl = bbase[blockIdx.x] + ws[wave] + x - c;
        row_ptr[i] = excl;
        cursor[i] = excl;
        dinv[i] = rsqrtf((float)c);
    }
}

__global__ void k_scatter(const int* __restrict__ src, const int* __restrict__ dst, int E, int N,
                          int* __restrict__ cursor, int* __restrict__ col) {
    int t = blockIdx.x * blockDim.x + threadIdx.x;
    if (t < E) {
        int p = atomicAdd(&cursor[dst[t]], 1);
        col[p] = src[t];
    } else if (t < E + N) {
        int n = t - E;
        int p = atomicAdd(&cursor[n], 1);
        col[p] = n;
    }
}

// ---------------- GEMM1 (barrier-free, 32-row x 256-col tiles) ----------------
// y[bf16, N x 256] = xb @ W1t^T  (unnormalized; dinv applied in agg)
__global__ __launch_bounds__(256) void k_gemm1(const unsigned short* __restrict__ xb,
                                               const unsigned short* __restrict__ W1t,
                                               unsigned short* __restrict__ y, int N, int K) {
    const int tid = threadIdx.x;
    const int wave = tid >> 6, lane = tid & 63;
    const int quad = lane >> 4, l16 = lane & 15;
    const int row0 = blockIdx.x * 32;
    const int n0 = wave * 64;
    f32x4 acc[2][4] = {};
    const unsigned short* ap[2];
#pragma unroll
    for (int i = 0; i < 2; ++i) ap[i] = xb + (size_t)min(row0 + i * 16 + l16, N - 1) * K + quad * 8;
    const unsigned short* bp = W1t + (size_t)(n0 + l16) * K + quad * 8;
#pragma unroll 2
    for (int k0 = 0; k0 < K; k0 += 32) {
        bf16x8 afr[2], bfr[4];
#pragma unroll
        for (int i = 0; i < 2; ++i) afr[i] = *(const bf16x8*)(ap[i] + k0);
#pragma unroll
        for (int j = 0; j < 4; ++j) bfr[j] = *(const bf16x8*)(bp + (size_t)j * 16 * K + k0);
#pragma unroll
        for (int i = 0; i < 2; ++i)
#pragma unroll
            for (int j = 0; j < 4; ++j)
                acc[i][j] = __builtin_amdgcn_mfma_f32_16x16x32_bf16(afr[i], bfr[j], acc[i][j], 0, 0, 0);
    }
#pragma unroll
    for (int i = 0; i < 2; ++i) {
        const int gr = row0 + i * 16 + quad * 4;
#pragma unroll
        for (int r = 0; r < 4; ++r) {
            const int row = gr + r;
            if (row < N) {
#pragma unroll
                for (int j = 0; j < 4; ++j)
                    y[(size_t)row * 256 + n0 + j * 16 + l16] = f2bf(acc[i][j][r]);
            }
        }
    }
}

// ---------------- GEMM2 (barrier-free, 32-row tiles): out[2,N,Cout] = g @ [Wmu|Wls] + bias ----------------
__global__ __launch_bounds__(256) void k_gemm2(const unsigned short* __restrict__ g,
                                               const unsigned short* __restrict__ Wct,
                                               const float* __restrict__ bmu, const float* __restrict__ bls,
                                               float* __restrict__ out, int N, int Cout) {
    const int K = 256;
    const int tid = threadIdx.x;
    const int wave = tid >> 6, lane = tid & 63;
    const int quad = lane >> 4, l16 = lane & 15;
    const int row0 = blockIdx.x * 32;
    const int n0 = wave * 64;
    f32x4 acc[2][4] = {};
    const unsigned short* ap[2];
#pragma unroll
    for (int i = 0; i < 2; ++i) ap[i] = g + (size_t)min(row0 + i * 16 + l16, N - 1) * K + quad * 8;
    const unsigned short* bp = Wct + (size_t)(n0 + l16) * K + quad * 8;
#pragma unroll 2
    for (int k0 = 0; k0 < K; k0 += 32) {
        bf16x8 afr[2], bfr[4];
#pragma unroll
        for (int i = 0; i < 2; ++i) afr[i] = *(const bf16x8*)(ap[i] + k0);
#pragma unroll
        for (int j = 0; j < 4; ++j) bfr[j] = *(const bf16x8*)(bp + (size_t)j * 16 * K + k0);
#pragma unroll
        for (int i = 0; i < 2; ++i)
#pragma unroll
            for (int j = 0; j < 4; ++j)
                acc[i][j] = __builtin_amdgcn_mfma_f32_16x16x32_bf16(afr[i], bfr[j], acc[i][j], 0, 0, 0);
    }
#pragma unroll
    for (int j = 0; j < 4; ++j) {
        const int c = n0 + j * 16 + l16;
        const bool is_mu = (c < Cout);
        const int ocl = is_mu ? c : (c - Cout);
        const float bv = is_mu ? bmu[ocl] : bls[ocl];
        const size_t obase = is_mu ? 0 : (size_t)N * Cout;
#pragma unroll
        for (int i = 0; i < 2; ++i) {
            const int gr = row0 + i * 16 + quad * 4;
#pragma unroll
            for (int r = 0; r < 4; ++r) {
                const int row = gr + r;
                if (row < N) out[obase + (size_t)row * Cout + ocl] = acc[i][j][r] + bv;
            }
        }
    }
}

// ---------------- CSR aggregation with per-neighbor dinv[src] ----------------
// relu_mode=1: Yout[n] = bf16( relu(dinv[n]*sum_s dinv[s]*Yin[s] + bias) )
// relu_mode=0: Yout[n] = bf16( dinv[n]*sum_s dinv[s]*Yin[s] )
__global__ __launch_bounds__(256) void k_agg(const unsigned short* __restrict__ Yin,
                                             const int* __restrict__ row_ptr, const int* __restrict__ col,
                                             const float* __restrict__ dinv, const float* __restrict__ bias,
                                             unsigned short* __restrict__ Yout, int N, int relu_mode) {
    const int n = blockIdx.x * 4 + (threadIdx.x >> 6);
    if (n >= N) return;
    const int lane = threadIdx.x & 63;
    const int c = lane * 4;
    const int jb = row_ptr[n], je = row_ptr[n + 1];
    float ax0 = 0.f, ay0 = 0.f, az0 = 0.f, aw0 = 0.f;
    float ax1 = 0.f, ay1 = 0.f, az1 = 0.f, aw1 = 0.f;
    int j = jb;
    for (; j + 3 < je; j += 4) {
        const int s0 = col[j], s1 = col[j + 1], s2 = col[j + 2], s3 = col[j + 3];
        const float d0 = dinv[s0], d1 = dinv[s1], d2 = dinv[s2], d3 = dinv[s3];
        const uint2 v0 = *(const uint2*)(Yin + (size_t)s0 * 256 + c);
        const uint2 v1 = *(const uint2*)(Yin + (size_t)s1 * 256 + c);
        const uint2 v2 = *(const uint2*)(Yin + (size_t)s2 * 256 + c);
        const uint2 v3 = *(const uint2*)(Yin + (size_t)s3 * 256 + c);
        ax0 = fmaf(d0, blo(v0.x), fmaf(d1, blo(v1.x), ax0));
        ay0 = fmaf(d0, bhi(v0.x), fmaf(d1, bhi(v1.x), ay0));
        az0 = fmaf(d0, blo(v0.y), fmaf(d1, blo(v1.y), az0));
        aw0 = fmaf(d0, bhi(v0.y), fmaf(d1, bhi(v1.y), aw0));
        ax1 = fmaf(d2, blo(v2.x), fmaf(d3, blo(v3.x), ax1));
        ay1 = fmaf(d2, bhi(v2.x), fmaf(d3, bhi(v3.x), ay1));
        az1 = fmaf(d2, blo(v2.y), fmaf(d3, blo(v3.y), az1));
        aw1 = fmaf(d2, bhi(v2.y), fmaf(d3, bhi(v3.y), aw1));
    }
    for (; j < je; ++j) {
        const int s0 = col[j];
        const float d0 = dinv[s0];
        const uint2 v0 = *(const uint2*)(Yin + (size_t)s0 * 256 + c);
        ax0 = fmaf(d0, blo(v0.x), ax0);
        ay0 = fmaf(d0, bhi(v0.x), ay0);
        az0 = fmaf(d0, blo(v0.y), az0);
        aw0 = fmaf(d0, bhi(v0.y), aw0);
    }
    const float ax = ax0 + ax1, ay = ay0 + ay1, az = az0 + az1, aw = aw0 + aw1;
    const float dn = dinv[n];
    float ox, oy, oz, ow;
    if (relu_mode) {
        const float4 b = *(const float4*)&bias[c];
        ox = fmaxf(fmaf(dn, ax, b.x), 0.f);
        oy = fmaxf(fmaf(dn, ay, b.y), 0.f);
        oz = fmaxf(fmaf(dn, az, b.z), 0.f);
        ow = fmaxf(fmaf(dn, aw, b.w), 0.f);
    } else {
        ox = dn * ax; oy = dn * ay; oz = dn * az; ow = dn * aw;
    }
    uint2 o;
    o.x = (unsigned)f2bf(ox) | ((unsigned)f2bf(oy) << 16);
    o.y = (unsigned)f2bf(oz) | ((unsigned)f2bf(ow) << 16);
    *(uint2*)(Yout + (size_t)n * 256 + c) = o;
}

// ---------------- launch ----------------

extern "C" void kernel_launch(void* const* d_in, const int* in_sizes, int n_in,
                              void* d_out, int out_size, void* d_ws, size_t ws_size,
                              hipStream_t stream) {
    const float* x   = (const float*)d_in[0];
    const int*   ei  = (const int*)d_in[1];
    const float* W1  = (const float*)d_in[2];
    const float* b1  = (const float*)d_in[3];
    const float* Wmu = (const float*)d_in[4];
    const float* bmu = (const float*)d_in[5];
    const float* Wls = (const float*)d_in[6];
    const float* bls = (const float*)d_in[7];

    const int H    = in_sizes[3];        // 256
    const int Cin  = in_sizes[2] / H;    // 512
    const int Cout = in_sizes[5];        // 128
    const int N    = in_sizes[0] / Cin;  // 50000
    const int E    = in_sizes[1] / 2;    // 800000
    const int* srcv = ei;
    const int* dstv = ei + E;

    char* w = (char*)d_ws;
    size_t off = 0;
    auto alloc = [&](size_t bytes) -> void* {
        void* p = w + off;
        off = (off + bytes + 255) & ~(size_t)255;
        return p;
    };
    const int nb = ceil_div(N, 256);
    int*            cnt     = (int*)alloc((size_t)N * 4);
    int*            cursor  = (int*)alloc((size_t)N * 4);
    int*            row_ptr = (int*)alloc((size_t)(N + 1) * 4);
    float*          dinv    = (float*)alloc((size_t)N * 4);
    int*            bsum    = (int*)alloc((size_t)nb * 4);
    int*            bbase   = (int*)alloc((size_t)nb * 4);
    int*            col     = (int*)alloc((size_t)(E + N) * 4);
    unsigned short* W1t     = (unsigned short*)alloc((size_t)H * Cin * 2);
    unsigned short* Wct     = (unsigned short*)alloc((size_t)2 * Cout * H * 2);
    unsigned short* xb      = (unsigned short*)alloc((size_t)N * Cin * 2);
    unsigned short* y       = (unsigned short*)alloc((size_t)N * H * 2);
    unsigned short* y2      = (unsigned short*)alloc((size_t)N * H * 2);
    unsigned short* g       = y;  // y dead after agg1; reuse
    (void)ws_size; (void)n_in; (void)out_size;

    hipMemsetAsync(cnt, 0, (size_t)N * 4, stream);

    const long nx = (long)N * Cin;
    const int nbCount = ceil_div(E, 256);
    const int nbX = (int)((nx + 2047) / 2048);
    const int nbW = ceil_div(H * Cin + 2 * Cout * H, 256);
    k_prep<<<nbCount + nbX + nbW, 256, 0, stream>>>(dstv, E, cnt, x, xb, nx, W1, Wmu, Wls, W1t, Wct,
                                                    Cin, H, Cout, nbCount, nbX);

    k_bsum<<<nb, 256, 0, stream>>>(cnt, bsum, N);
    k_scan_bsum<<<1, 256, 0, stream>>>(bsum, bbase, nb, row_ptr, N);
    k_scan_apply<<<nb, 256, 0, stream>>>(cnt, bbase, row_ptr, cursor, dinv, N);
    k_scatter<<<ceil_div(E + N, 256), 256, 0, stream>>>(srcv, dstv, E, N, cursor, col);

    k_gemm1<<<ceil_div(N, 32), 256, 0, stream>>>(xb, W1t, y, N, Cin);

    k_agg<<<ceil_div(N, 4), 256, 0, stream>>>(y, row_ptr, col, dinv, b1, y2, N, 1);
    k_agg<<<ceil_div(N, 4), 256, 0, stream>>>(y2, row_ptr, col, dinv, nullptr, g, N, 0);

    k_gemm2<<<ceil_div(N, 32), 256, 0, stream>>>(g, Wct, bmu, bls, (float*)d_out, N, Cout);
}

// Round 6
// 453.785 us; speedup vs baseline: 1.1522x; 1.1522x over previous
//
#include <hip/hip_runtime.h>

static inline int ceil_div(int a, int b) { return (a + b - 1) / b; }

typedef __attribute__((ext_vector_type(8))) __bf16 bf16x8;
typedef __attribute__((ext_vector_type(8))) unsigned short ushort8;
typedef __attribute__((ext_vector_type(4))) float f32x4;

__device__ __forceinline__ unsigned short f2bf(float f) {
    union { float f; unsigned u; } v; v.f = f;
    unsigned r = v.u + 0x7fffu + ((v.u >> 16) & 1u);
    return (unsigned short)(r >> 16);
}
__device__ __forceinline__ float blo(unsigned u) {
    union { unsigned u; float f; } x; x.u = u << 16; return x.f;
}
__device__ __forceinline__ float bhi(unsigned u) {
    union { unsigned u; float f; } x; x.u = u & 0xffff0000u; return x.f;
}

// 16B chunk swizzle: chunk c of row r stored at slot (c ^ swz(r)); 2-way bank aliasing only (free).
#define SWZ(r) ((((r) & 3) ^ (((r) >> 2) & 3)))

typedef __attribute__((address_space(3))) unsigned lds_uint;
typedef __attribute__((address_space(1))) const unsigned glb_uint;
__device__ __forceinline__ void gload_lds16(const unsigned short* g, unsigned short* l) {
    __builtin_amdgcn_global_load_lds((glb_uint*)g, (lds_uint*)l, 16, 0, 0);
}

// ---------------- fused prep: edge count + x->bf16 + weight transpose ----------------
__global__ __launch_bounds__(256) void k_prep(const int* __restrict__ dst, int E, int* __restrict__ cnt,
                                              const float* __restrict__ x, unsigned short* __restrict__ xb,
                                              long nx,
                                              const float* __restrict__ W1, const float* __restrict__ Wmu,
                                              const float* __restrict__ Wls, unsigned short* __restrict__ W1t,
                                              unsigned short* __restrict__ Wct, int K1, int H, int Cout,
                                              int nbCount, int nbX) {
    const int b = blockIdx.x;
    if (b < nbCount) {
        int e = b * 256 + threadIdx.x;
        if (e < E) atomicAdd(&cnt[dst[e]], 1);
    } else if (b < nbCount + nbX) {
        long i = (long)(b - nbCount) * 2048 + (long)threadIdx.x * 8;
        if (i < nx) {
            float4 a0 = *(const float4*)(x + i);
            float4 a1 = *(const float4*)(x + i + 4);
            ushort8 t;
            t[0] = f2bf(a0.x); t[1] = f2bf(a0.y); t[2] = f2bf(a0.z); t[3] = f2bf(a0.w);
            t[4] = f2bf(a1.x); t[5] = f2bf(a1.y); t[6] = f2bf(a1.z); t[7] = f2bf(a1.w);
            *(ushort8*)(xb + i) = t;
        }
    } else {
        int t = (b - nbCount - nbX) * 256 + threadIdx.x;
        int n1 = H * K1;
        int n2 = 2 * Cout * H;
        if (t < n1) {
            int c = t / K1, k = t - c * K1;
            W1t[t] = f2bf(W1[(size_t)k * H + c]);
        } else if (t < n1 + n2) {
            int u = t - n1;
            int c = u / H, k = u - c * H;
            float v = (c < Cout) ? Wmu[(size_t)k * Cout + c] : Wls[(size_t)k * Cout + (c - Cout)];
            Wct[u] = f2bf(v);
        }
    }
}

// ---- hierarchical exclusive scan over deg = cnt+1 (self-loop) ----
__global__ __launch_bounds__(256) void k_bsum(const int* __restrict__ cnt, int* __restrict__ bsum, int N) {
    __shared__ int ws[4];
    const int i = blockIdx.x * 256 + threadIdx.x;
    const int lane = threadIdx.x & 63, wave = threadIdx.x >> 6;
    int v = (i < N) ? cnt[i] + 1 : 0;
    for (int off = 32; off > 0; off >>= 1) v += __shfl_down(v, off);
    if (lane == 0) ws[wave] = v;
    __syncthreads();
    if (threadIdx.x == 0) bsum[blockIdx.x] = ws[0] + ws[1] + ws[2] + ws[3];
}

__global__ __launch_bounds__(256) void k_scan_bsum(const int* __restrict__ bsum, int* __restrict__ bbase,
                                                   int nb, int* __restrict__ row_ptr, int N) {
    __shared__ int ws[4];
    const int tid = threadIdx.x;
    const int lane = tid & 63, wave = tid >> 6;
    const int v = (tid < nb) ? bsum[tid] : 0;
    int x = v;
    for (int off = 1; off < 64; off <<= 1) {
        int t = __shfl_up(x, off);
        if (lane >= off) x += t;
    }
    if (lane == 63) ws[wave] = x;
    __syncthreads();
    if (tid == 0) {
        int r = 0;
        for (int i = 0; i < 4; ++i) { int t = ws[i]; ws[i] = r; r += t; }
        row_ptr[N] = r;
    }
    __syncthreads();
    if (tid < nb) bbase[tid] = ws[wave] + x - v;
}

__global__ __launch_bounds__(256) void k_scan_apply(const int* __restrict__ cnt, const int* __restrict__ bbase,
                                                    int* __restrict__ row_ptr, int* __restrict__ cursor,
                                                    float* __restrict__ dinv, int N) {
    __shared__ int ws[4];
    const int i = blockIdx.x * 256 + threadIdx.x;
    const int lane = threadIdx.x & 63, wave = threadIdx.x >> 6;
    const int c = (i < N) ? cnt[i] + 1 : 0;
    int x = c;
    for (int off = 1; off < 64; off <<= 1) {
        int t = __shfl_up(x, off);
        if (lane >= off) x += t;
    }
    if (lane == 63) ws[wave] = x;
    __syncthreads();
    if (threadIdx.x == 0) {
        int r = 0;
        for (int k = 0; k < 4; ++k) { int t = ws[k]; ws[k] = r; r += t; }
    }
    __syncthreads();
    if (i < N) {
        const int excl = bbase[blockIdx.x] + ws[wave] + x - c;
        row_ptr[i] = excl;
        cursor[i] = excl;
        dinv[i] = rsqrtf((float)c);
    }
}

__global__ void k_scatter(const int* __restrict__ src, const int* __restrict__ dst, int E, int N,
                          int* __restrict__ cursor, int* __restrict__ col) {
    int t = blockIdx.x * blockDim.x + threadIdx.x;
    if (t < E) {
        int p = atomicAdd(&cursor[dst[t]], 1);
        col[p] = src[t];
    } else if (t < E + N) {
        int n = t - E;
        int p = atomicAdd(&cursor[n], 1);
        col[p] = n;
    }
}

// ---------------- m97-style GEMM core: 128x128 tile, BK=32, global_load_lds + swizzled LDS ----------------
// A: M x K bf16 row-major (row stride K, 16B-aligned rows). B: 128-col slice rows = output cols, K cols.
// Each block: rows [row0,row0+128) x cols [col0,col0+128). Wave (rw,cw) does 64x64.
// OOB rows read garbage inside d_ws (masked at store).
__device__ __forceinline__ void gemm_tile_core(const unsigned short* __restrict__ A,
                                               const unsigned short* __restrict__ B,
                                               unsigned short* __restrict__ As, unsigned short* __restrict__ Bs,
                                               int row0, int col0, int K,
                                               int wave, int lane, f32x4 (*acc)[4]) {
    const int quad = lane >> 4, l16 = lane & 15;
    const int rw = wave & 1, cw = wave >> 1;
    const int srow = wave * 32 + (lane >> 2);   // staging row handled by this lane (first of two)
    const int slot = lane & 3;
    for (int k0 = 0; k0 < K; k0 += 32) {
#pragma unroll
        for (int t = 0; t < 2; ++t) {
            const int lr = srow + t * 16;
            const int kc = (slot ^ SWZ(lr)) * 8;
            gload_lds16(A + (size_t)(row0 + lr) * K + k0 + kc, As + (wave * 32 + t * 16) * 32);
            gload_lds16(B + (size_t)(col0 + lr) * K + k0 + kc, Bs + (wave * 32 + t * 16) * 32);
        }
        __syncthreads();
        bf16x8 af[4], bf[4];
#pragma unroll
        for (int i = 0; i < 4; ++i) {
            const int lr = rw * 64 + i * 16 + l16;
            af[i] = *(const bf16x8*)&As[lr * 32 + ((quad ^ SWZ(lr))) * 8];
            const int lc = cw * 64 + i * 16 + l16;
            bf[i] = *(const bf16x8*)&Bs[lc * 32 + ((quad ^ SWZ(lc))) * 8];
        }
#pragma unroll
        for (int i = 0; i < 4; ++i)
#pragma unroll
            for (int j = 0; j < 4; ++j)
                acc[i][j] = __builtin_amdgcn_mfma_f32_16x16x32_bf16(af[i], bf[j], acc[i][j], 0, 0, 0);
        __syncthreads();
    }
}

// GEMM1: y[bf16, N x 256] = xb @ W1t^T (unnormalized; dinv applied in agg)
__global__ __launch_bounds__(256) void k_gemm1(const unsigned short* __restrict__ xb,
                                               const unsigned short* __restrict__ W1t,
                                               unsigned short* __restrict__ y, int N, int K) {
    __shared__ __align__(16) unsigned short As[128 * 32];
    __shared__ __align__(16) unsigned short Bs[128 * 32];
    const int tid = threadIdx.x, wave = tid >> 6, lane = tid & 63;
    const int quad = lane >> 4, l16 = lane & 15;
    const int row0 = blockIdx.x * 128, col0 = blockIdx.y * 128;
    const int rw = wave & 1, cw = wave >> 1;
    f32x4 acc[4][4] = {};
    gemm_tile_core(xb, W1t, As, Bs, row0, col0, K, wave, lane, acc);
#pragma unroll
    for (int i = 0; i < 4; ++i) {
        const int grb = row0 + rw * 64 + i * 16 + quad * 4;
#pragma unroll
        for (int r = 0; r < 4; ++r) {
            const int row = grb + r;
            if (row < N) {
#pragma unroll
                for (int j = 0; j < 4; ++j)
                    y[(size_t)row * 256 + col0 + cw * 64 + j * 16 + l16] = f2bf(acc[i][j][r]);
            }
        }
    }
}

// GEMM2: out[2,N,Cout] = g @ [Wmu|Wls] + bias
__global__ __launch_bounds__(256) void k_gemm2(const unsigned short* __restrict__ g,
                                               const unsigned short* __restrict__ Wct,
                                               const float* __restrict__ bmu, const float* __restrict__ bls,
                                               float* __restrict__ out, int N, int Cout) {
    __shared__ __align__(16) unsigned short As[128 * 32];
    __shared__ __align__(16) unsigned short Bs[128 * 32];
    const int K = 256;
    const int tid = threadIdx.x, wave = tid >> 6, lane = tid & 63;
    const int quad = lane >> 4, l16 = lane & 15;
    const int row0 = blockIdx.x * 128, col0 = blockIdx.y * 128;
    const int rw = wave & 1, cw = wave >> 1;
    f32x4 acc[4][4] = {};
    gemm_tile_core(g, Wct, As, Bs, row0, col0, K, wave, lane, acc);
#pragma unroll
    for (int j = 0; j < 4; ++j) {
        const int c = col0 + cw * 64 + j * 16 + l16;
        const bool is_mu = (c < Cout);
        const int ocl = is_mu ? c : (c - Cout);
        const float bv = is_mu ? bmu[ocl] : bls[ocl];
        const size_t obase = is_mu ? 0 : (size_t)N * Cout;
#pragma unroll
        for (int i = 0; i < 4; ++i) {
            const int grb = row0 + rw * 64 + i * 16 + quad * 4;
#pragma unroll
            for (int r = 0; r < 4; ++r) {
                const int row = grb + r;
                if (row < N) out[obase + (size_t)row * Cout + ocl] = acc[i][j][r] + bv;
            }
        }
    }
}

// ---------------- CSR aggregation with per-neighbor dinv[src] ----------------
// relu_mode=1: Yout[n] = bf16( relu(dinv[n]*sum_s dinv[s]*Yin[s] + bias) )
// relu_mode=0: Yout[n] = bf16( dinv[n]*sum_s dinv[s]*Yin[s] )
__global__ __launch_bounds__(256) void k_agg(const unsigned short* __restrict__ Yin,
                                             const int* __restrict__ row_ptr, const int* __restrict__ col,
                                             const float* __restrict__ dinv, const float* __restrict__ bias,
                                             unsigned short* __restrict__ Yout, int N, int relu_mode) {
    const int n = blockIdx.x * 4 + (threadIdx.x >> 6);
    if (n >= N) return;
    const int lane = threadIdx.x & 63;
    const int c = lane * 4;
    const int jb = row_ptr[n], je = row_ptr[n + 1];
    float ax0 = 0.f, ay0 = 0.f, az0 = 0.f, aw0 = 0.f;
    float ax1 = 0.f, ay1 = 0.f, az1 = 0.f, aw1 = 0.f;
    int j = jb;
    for (; j + 3 < je; j += 4) {
        const int s0 = col[j], s1 = col[j + 1], s2 = col[j + 2], s3 = col[j + 3];
        const float d0 = dinv[s0], d1 = dinv[s1], d2 = dinv[s2], d3 = dinv[s3];
        const uint2 v0 = *(const uint2*)(Yin + (size_t)s0 * 256 + c);
        const uint2 v1 = *(const uint2*)(Yin + (size_t)s1 * 256 + c);
        const uint2 v2 = *(const uint2*)(Yin + (size_t)s2 * 256 + c);
        const uint2 v3 = *(const uint2*)(Yin + (size_t)s3 * 256 + c);
        ax0 = fmaf(d0, blo(v0.x), fmaf(d1, blo(v1.x), ax0));
        ay0 = fmaf(d0, bhi(v0.x), fmaf(d1, bhi(v1.x), ay0));
        az0 = fmaf(d0, blo(v0.y), fmaf(d1, blo(v1.y), az0));
        aw0 = fmaf(d0, bhi(v0.y), fmaf(d1, bhi(v1.y), aw0));
        ax1 = fmaf(d2, blo(v2.x), fmaf(d3, blo(v3.x), ax1));
        ay1 = fmaf(d2, bhi(v2.x), fmaf(d3, bhi(v3.x), ay1));
        az1 = fmaf(d2, blo(v2.y), fmaf(d3, blo(v3.y), az1));
        aw1 = fmaf(d2, bhi(v2.y), fmaf(d3, bhi(v3.y), aw1));
    }
    for (; j < je; ++j) {
        const int s0 = col[j];
        const float d0 = dinv[s0];
        const uint2 v0 = *(const uint2*)(Yin + (size_t)s0 * 256 + c);
        ax0 = fmaf(d0, blo(v0.x), ax0);
        ay0 = fmaf(d0, bhi(v0.x), ay0);
        az0 = fmaf(d0, blo(v0.y), az0);
        aw0 = fmaf(d0, bhi(v0.y), aw0);
    }
    const float ax = ax0 + ax1, ay = ay0 + ay1, az = az0 + az1, aw = aw0 + aw1;
    const float dn = dinv[n];
    float ox, oy, oz, ow;
    if (relu_mode) {
        const float4 b = *(const float4*)&bias[c];
        ox = fmaxf(fmaf(dn, ax, b.x), 0.f);
        oy = fmaxf(fmaf(dn, ay, b.y), 0.f);
        oz = fmaxf(fmaf(dn, az, b.z), 0.f);
        ow = fmaxf(fmaf(dn, aw, b.w), 0.f);
    } else {
        ox = dn * ax; oy = dn * ay; oz = dn * az; ow = dn * aw;
    }
    uint2 o;
    o.x = (unsigned)f2bf(ox) | ((unsigned)f2bf(oy) << 16);
    o.y = (unsigned)f2bf(oz) | ((unsigned)f2bf(ow) << 16);
    *(uint2*)(Yout + (size_t)n * 256 + c) = o;
}

// ---------------- launch ----------------

extern "C" void kernel_launch(void* const* d_in, const int* in_sizes, int n_in,
                              void* d_out, int out_size, void* d_ws, size_t ws_size,
                              hipStream_t stream) {
    const float* x   = (const float*)d_in[0];
    const int*   ei  = (const int*)d_in[1];
    const float* W1  = (const float*)d_in[2];
    const float* b1  = (const float*)d_in[3];
    const float* Wmu = (const float*)d_in[4];
    const float* bmu = (const float*)d_in[5];
    const float* Wls = (const float*)d_in[6];
    const float* bls = (const float*)d_in[7];

    const int H    = in_sizes[3];        // 256
    const int Cin  = in_sizes[2] / H;    // 512
    const int Cout = in_sizes[5];        // 128
    const int N    = in_sizes[0] / Cin;  // 50000
    const int E    = in_sizes[1] / 2;    // 800000
    const int* srcv = ei;
    const int* dstv = ei + E;

    char* w = (char*)d_ws;
    size_t off = 0;
    auto alloc = [&](size_t bytes) -> void* {
        void* p = w + off;
        off = (off + bytes + 255) & ~(size_t)255;
        return p;
    };
    const int nb = ceil_div(N, 256);
    int*            cnt     = (int*)alloc((size_t)N * 4);
    int*            cursor  = (int*)alloc((size_t)N * 4);
    int*            row_ptr = (int*)alloc((size_t)(N + 1) * 4);
    float*          dinv    = (float*)alloc((size_t)N * 4);
    int*            bsum    = (int*)alloc((size_t)nb * 4);
    int*            bbase   = (int*)alloc((size_t)nb * 4);
    int*            col     = (int*)alloc((size_t)(E + N) * 4);
    unsigned short* W1t     = (unsigned short*)alloc((size_t)H * Cin * 2);
    unsigned short* Wct     = (unsigned short*)alloc((size_t)2 * Cout * H * 2);
    unsigned short* xb      = (unsigned short*)alloc((size_t)N * Cin * 2);
    unsigned short* y       = (unsigned short*)alloc((size_t)N * H * 2);
    unsigned short* y2      = (unsigned short*)alloc((size_t)(N + 128) * H * 2);  // +tail pad for OOB tile reads
    unsigned short* g       = y;  // y dead after agg1; reuse
    (void)ws_size; (void)n_in; (void)out_size;

    hipMemsetAsync(cnt, 0, (size_t)N * 4, stream);

    const long nx = (long)N * Cin;
    const int nbCount = ceil_div(E, 256);
    const int nbX = (int)((nx + 2047) / 2048);
    const int nbW = ceil_div(H * Cin + 2 * Cout * H, 256);
    k_prep<<<nbCount + nbX + nbW, 256, 0, stream>>>(dstv, E, cnt, x, xb, nx, W1, Wmu, Wls, W1t, Wct,
                                                    Cin, H, Cout, nbCount, nbX);

    k_bsum<<<nb, 256, 0, stream>>>(cnt, bsum, N);
    k_scan_bsum<<<1, 256, 0, stream>>>(bsum, bbase, nb, row_ptr, N);
    k_scan_apply<<<nb, 256, 0, stream>>>(cnt, bbase, row_ptr, cursor, dinv, N);
    k_scatter<<<ceil_div(E + N, 256), 256, 0, stream>>>(srcv, dstv, E, N, cursor, col);

    dim3 g1(ceil_div(N, 128), 2);
    k_gemm1<<<g1, 256, 0, stream>>>(xb, W1t, y, N, Cin);

    k_agg<<<ceil_div(N, 4), 256, 0, stream>>>(y, row_ptr, col, dinv, b1, y2, N, 1);
    k_agg<<<ceil_div(N, 4), 256, 0, stream>>>(y2, row_ptr, col, dinv, nullptr, g, N, 0);

    dim3 g2(ceil_div(N, 128), 2);
    k_gemm2<<<g2, 256, 0, stream>>>(g, Wct, bmu, bls, (float*)d_out, N, Cout);
}